// Round 6
// baseline (378.609 us; speedup 1.0000x reference)
//
#include <hip/hip_runtime.h>
#include <cstdint>
#include <cstddef>

#define HIDDEN 128
#define N_NODES_C 50000

typedef short bf16x8 __attribute__((ext_vector_type(8)));   // 8 bf16 in 4 VGPRs
typedef unsigned short u16x8 __attribute__((ext_vector_type(8)));
typedef float f32x4 __attribute__((ext_vector_type(4)));

__device__ inline unsigned short f2b(float x) {   // fp32 -> bf16 RNE
    union { float f; unsigned int u; } v; v.f = x;
    unsigned int r = v.u + 0x7FFFu + ((v.u >> 16) & 1u);
    return (unsigned short)(r >> 16);
}
__device__ inline float b2f(unsigned short h) {
    union { unsigned int u; float f; } v; v.u = ((unsigned int)h) << 16;
    return v.f;
}

// ---- prep: bf16 transposed weights (113 blocks) + zero deg ----
// blocks 0..15: encT rows; 16..63: six 128x128 matrices (8 blocks each);
// 64..112: zero deg.
__global__ __launch_bounds__(256) void prep_kernel(
    const float* __restrict__ enc_w, const float* __restrict__ p1a_w,
    const float* __restrict__ lin1_w, const float* __restrict__ p2a_w,
    const float* __restrict__ lin2_w,
    unsigned short* __restrict__ encT,
    unsigned short* __restrict__ A1T, unsigned short* __restrict__ B1T,
    unsigned short* __restrict__ L1T,
    unsigned short* __restrict__ A2T, unsigned short* __restrict__ B2T,
    unsigned short* __restrict__ L2T,
    int* __restrict__ deg, int M)
{
    const int b = blockIdx.x, t = threadIdx.x;
    if (b < 16) {            // encT [128][256] from enc_w [256][128]; 8 rows/block
        for (int i = t; i < 8 * 256; i += 256) {
            int n = b * 8 + (i >> 8);
            int k = i & 255;
            encT[n * 256 + k] = f2b(enc_w[k * 128 + n]);
        }
    } else if (b < 64) {     // [128][128] transposes; 16 rows per block
        const int mi  = (b - 16) >> 3;
        const int sub = (b - 16) & 7;
        const float* src; unsigned short* dst;
        switch (mi) {
            case 0: src = p1a_w;              dst = A1T; break;
            case 1: src = p1a_w + 128 * 128;  dst = B1T; break;
            case 2: src = lin1_w;             dst = L1T; break;
            case 3: src = p2a_w;              dst = A2T; break;
            case 4: src = p2a_w + 128 * 128;  dst = B2T; break;
            default: src = lin2_w;            dst = L2T; break;
        }
        for (int i = t; i < 16 * 128; i += 256) {
            int n = sub * 16 + (i >> 7);
            int k = i & 127;
            dst[n * 128 + k] = f2b(src[k * 128 + n]);
        }
    } else {                 // zero deg
        const int base = (b - 64) * 1024 + t * 4;
        if (base + 3 < M) *(int4*)(deg + base) = make_int4(0, 0, 0, 0);
        else for (int j = 0; j < 4; ++j) if (base + j < M) deg[base + j] = 0;
    }
}

// ---- encoder: h0 = relu(x @ enc_w + enc_b), bf16 out. MFMA 16x16x32. ----
__global__ __launch_bounds__(256) void enc_mfma(
    const float* __restrict__ x, const unsigned short* __restrict__ encT,
    const float* __restrict__ enc_b, unsigned short* __restrict__ h0, int M)
{
    const int wave = threadIdx.x >> 6, lane = threadIdx.x & 63;
    const int rowBase = blockIdx.x * 64 + wave * 16;
    const int sl = lane & 15, kg = lane >> 4;
    const int row_a = rowBase + sl;

    f32x4 acc[8] = {};
    for (int ks = 0; ks < 8; ++ks) {
        const int k0 = ks * 32 + kg * 8;
        bf16x8 a = {};
        if (row_a < M) {
            const float* xp = x + (size_t)row_a * 256 + k0;
            float4 f0 = *(const float4*)xp;
            float4 f1 = *(const float4*)(xp + 4);
            a[0] = (short)f2b(f0.x); a[1] = (short)f2b(f0.y);
            a[2] = (short)f2b(f0.z); a[3] = (short)f2b(f0.w);
            a[4] = (short)f2b(f1.x); a[5] = (short)f2b(f1.y);
            a[6] = (short)f2b(f1.z); a[7] = (short)f2b(f1.w);
        }
        #pragma unroll
        for (int ct = 0; ct < 8; ++ct) {
            bf16x8 bfr = *(const bf16x8*)(encT + (size_t)(ct * 16 + sl) * 256 + k0);
            acc[ct] = __builtin_amdgcn_mfma_f32_16x16x32_bf16(a, bfr, acc[ct], 0, 0, 0);
        }
    }
    #pragma unroll
    for (int ct = 0; ct < 8; ++ct) {
        const int col = ct * 16 + sl;
        const float eb = enc_b[col];
        #pragma unroll
        for (int r = 0; r < 4; ++r) {
            const int row = rowBase + kg * 4 + r;
            if (row < M)
                h0[(size_t)row * 128 + col] = f2b(fmaxf(acc[ct][r] + eb, 0.f));
        }
    }
}

// ---- fused per-layer node precompute: A = h@AT', B = h@BT', L = h@LT'+linb ----
__global__ __launch_bounds__(256) void fused3_mfma(
    const unsigned short* __restrict__ h,
    const unsigned short* __restrict__ AT, const unsigned short* __restrict__ BT,
    const unsigned short* __restrict__ LT, const float* __restrict__ linb,
    unsigned short* __restrict__ outA, unsigned short* __restrict__ outB,
    unsigned short* __restrict__ outL, int M)
{
    const int wave = threadIdx.x >> 6, lane = threadIdx.x & 63;
    const int rowBase = blockIdx.x * 64 + wave * 16;
    const int sl = lane & 15, kg = lane >> 4;
    const int row_a = rowBase + sl;

    bf16x8 afr[4];
    #pragma unroll
    for (int ks = 0; ks < 4; ++ks) {
        if (row_a < M)
            afr[ks] = *(const bf16x8*)(h + (size_t)row_a * 128 + ks * 32 + kg * 8);
        else
            afr[ks] = bf16x8{};
    }

    #pragma unroll
    for (int m = 0; m < 3; ++m) {               // compile-time select (no scratch)
        const unsigned short* WT = (m == 0) ? AT : (m == 1) ? BT : LT;
        unsigned short* op       = (m == 0) ? outA : (m == 1) ? outB : outL;

        f32x4 acc[8] = {};
        #pragma unroll
        for (int ks = 0; ks < 4; ++ks) {
            const int k0 = ks * 32 + kg * 8;
            #pragma unroll
            for (int ct = 0; ct < 8; ++ct) {
                bf16x8 bfr = *(const bf16x8*)(WT + (size_t)(ct * 16 + sl) * 128 + k0);
                acc[ct] = __builtin_amdgcn_mfma_f32_16x16x32_bf16(afr[ks], bfr, acc[ct], 0, 0, 0);
            }
        }
        #pragma unroll
        for (int ct = 0; ct < 8; ++ct) {
            const int col = ct * 16 + sl;
            const float lb = (m == 2) ? linb[col] : 0.f;
            #pragma unroll
            for (int r = 0; r < 4; ++r) {
                const int row = rowBase + kg * 4 + r;
                if (row < M)
                    op[(size_t)row * 128 + col] = f2b(acc[ct][r] + lb);
            }
        }
    }
}

// ---- CSR build ----
__global__ __launch_bounds__(256) void hist_kernel(
    const int* __restrict__ ei, int E, int* __restrict__ deg)
{
    int e = blockIdx.x * 256 + threadIdx.x;
    if (e >= E) return;
    atomicAdd(&deg[ei[E + e]], 1);
}

// pass 1: per-1024 tile exclusive scan of deg -> arr[1+i]; block sums out
__global__ __launch_bounds__(256) void scan_blocks(
    const int* __restrict__ deg, int* __restrict__ arr,
    int* __restrict__ bsums, int M)
{
    __shared__ int part[256];
    const int t = threadIdx.x;
    const int base = blockIdx.x * 1024 + t * 4;

    int v0 = 0, v1 = 0, v2 = 0, v3 = 0;
    if (base + 3 < M) {
        int4 d = *(const int4*)(deg + base);
        v0 = d.x; v1 = d.y; v2 = d.z; v3 = d.w;
    } else {
        if (base + 0 < M) v0 = deg[base + 0];
        if (base + 1 < M) v1 = deg[base + 1];
        if (base + 2 < M) v2 = deg[base + 2];
    }
    part[t] = v0 + v1 + v2 + v3;
    __syncthreads();
    for (int off = 1; off < 256; off <<= 1) {
        int u = (t >= off) ? part[t - off] : 0;
        __syncthreads();
        part[t] += u;
        __syncthreads();
    }
    const int excl = (t == 0) ? 0 : part[t - 1];
    if (t == 255) bsums[blockIdx.x] = part[255];

    if (base + 0 < M) arr[1 + base + 0] = excl;
    if (base + 1 < M) arr[1 + base + 1] = excl + v0;
    if (base + 2 < M) arr[1 + base + 2] = excl + v0 + v1;
    if (base + 3 < M) arr[1 + base + 3] = excl + v0 + v1 + v2;
}

// pass 2 (merged fixup): every block wave-scans all bsums, adds its prefix.
__global__ __launch_bounds__(256) void scan_fixup(
    int* __restrict__ arr, const int* __restrict__ bsums, int nb, int M)
{
    __shared__ int pre;
    const int t = threadIdx.x;
    if (t < 64) {
        int v = (t < nb) ? bsums[t] : 0;
        #pragma unroll
        for (int off = 1; off < 64; off <<= 1) {
            int u = __shfl_up(v, off);
            if (t >= off) v += u;
        }
        const int myb = blockIdx.x;
        const int p = (myb == 0) ? 0 : __shfl(v, myb - 1);
        if (t == 0) pre = p;
    }
    __syncthreads();
    if (blockIdx.x == 0 && t == 0) arr[0] = 0;
    const int add = pre;
    if (add == 0) return;
    const int base = blockIdx.x * 1024 + t * 4;
    #pragma unroll
    for (int j = 0; j < 4; ++j)
        if (base + j < M) arr[1 + base + j] += add;
}

// scatter: atomicAdd on arr[1+d] converts shifted-exclusive scan into final
// CSR offsets (after all edges: arr[1+d] = offs[d+1]); no cursor array needed.
__global__ __launch_bounds__(256) void scatter_kernel(
    const int* __restrict__ ei, int E, int* __restrict__ arr,
    int* __restrict__ srcs)
{
    int e = blockIdx.x * 256 + threadIdx.x;
    if (e >= E) return;
    int d = ei[E + e];
    int pos = atomicAdd(&arr[1 + d], 1);
    srcs[pos] = ei[e];
}

// ---- gather: one wave per dst node, one edge per 16-lane group.
// CLS=false: store relu(acc) as bf16 to outH (layer 1).
// CLS=true : classifier fused; write out[node,2] fp32 (layer 2).
template<bool CLS>
__global__ __launch_bounds__(256) void gather_bf16(
    const int* __restrict__ arr, const int* __restrict__ srcs,
    const unsigned short* __restrict__ Amat, const unsigned short* __restrict__ Bmat,
    const unsigned short* __restrict__ Lmat,
    const float* __restrict__ hid_b, const float* __restrict__ pw,
    const float* __restrict__ pb,
    unsigned short* __restrict__ outH,
    const float* __restrict__ cls_w, const float* __restrict__ cls_b,
    float* __restrict__ outC, int M)
{
    const int node = blockIdx.x * 4 + (threadIdx.x >> 6);
    if (node >= M) return;
    const int lane = threadIdx.x & 63;
    const int grp = lane >> 4;          // which of 4 edges in flight
    const int sl  = lane & 15;
    const int c8  = sl * 8;             // 8 channels per lane

    float a[8], w[8];
    {
        u16x8 av = *(const u16x8*)(Amat + (size_t)node * 128 + c8);
        float4 h0 = *(const float4*)(hid_b + c8);
        float4 h1 = *(const float4*)(hid_b + c8 + 4);
        a[0] = b2f(av[0]) + h0.x; a[1] = b2f(av[1]) + h0.y;
        a[2] = b2f(av[2]) + h0.z; a[3] = b2f(av[3]) + h0.w;
        a[4] = b2f(av[4]) + h1.x; a[5] = b2f(av[5]) + h1.y;
        a[6] = b2f(av[6]) + h1.z; a[7] = b2f(av[7]) + h1.w;
        float4 p0 = *(const float4*)(pw + c8);
        float4 p1 = *(const float4*)(pw + c8 + 4);
        w[0] = p0.x; w[1] = p0.y; w[2] = p0.z; w[3] = p0.w;
        w[4] = p1.x; w[5] = p1.y; w[6] = p1.z; w[7] = p1.w;
    }
    const float pb0 = pb[0];
    float acc[8] = {};

    const int start = arr[node], end = arr[node + 1];
    // divergent per-group loop: each 16-lane group has a uniform trip count,
    // shfl widths <=8 stay inside the group.
    for (int idx = start + grp; idx < end; idx += 4) {
        const int s = srcs[idx];
        u16x8 bv = *(const u16x8*)(Bmat + (size_t)s * 128 + c8);
        u16x8 lv = *(const u16x8*)(Lmat + (size_t)s * 128 + c8);

        float part = 0.f;
        #pragma unroll
        for (int j = 0; j < 8; ++j)
            part += fmaxf(a[j] + b2f(bv[j]), 0.f) * w[j];
        part += __shfl_xor(part, 8);
        part += __shfl_xor(part, 4);
        part += __shfl_xor(part, 2);
        part += __shfl_xor(part, 1);

        const float pick = 1.f / (1.f + __expf(-(part + pb0)));
        #pragma unroll
        for (int j = 0; j < 8; ++j)
            acc[j] = fmaf(pick, b2f(lv[j]), acc[j]);
    }

    #pragma unroll
    for (int j = 0; j < 8; ++j) acc[j] += __shfl_xor(acc[j], 16);
    #pragma unroll
    for (int j = 0; j < 8; ++j) acc[j] += __shfl_xor(acc[j], 32);

    if (CLS) {
        // classifier fused: out[node,:] = acc(row) @ cls_w + cls_b
        float p0 = 0.f, p1 = 0.f;
        #pragma unroll
        for (int j = 0; j < 8; ++j) {
            p0 = fmaf(acc[j], cls_w[(c8 + j) * 2 + 0], p0);
            p1 = fmaf(acc[j], cls_w[(c8 + j) * 2 + 1], p1);
        }
        #pragma unroll
        for (int off = 8; off > 0; off >>= 1) {
            p0 += __shfl_xor(p0, off);
            p1 += __shfl_xor(p1, off);
        }
        if (lane == 0) {
            outC[(size_t)node * 2 + 0] = p0 + cls_b[0];
            outC[(size_t)node * 2 + 1] = p1 + cls_b[1];
        }
    } else {
        if (grp == 0) {
            u16x8 o;
            #pragma unroll
            for (int j = 0; j < 8; ++j)
                o[j] = f2b(fmaxf(acc[j], 0.f));     // relu before layer 2
            *(u16x8*)(outH + (size_t)node * 128 + c8) = o;
        }
    }
}

extern "C" void kernel_launch(void* const* d_in, const int* in_sizes, int n_in,
                              void* d_out, int out_size, void* d_ws, size_t ws_size,
                              hipStream_t stream)
{
    const float* x      = (const float*)d_in[0];
    const int*   ei     = (const int*)d_in[1];
    const float* enc_w  = (const float*)d_in[2];
    const float* enc_b  = (const float*)d_in[3];
    const float* lin1_w = (const float*)d_in[4];
    const float* lin1_b = (const float*)d_in[5];
    const float* p1a_w  = (const float*)d_in[6];
    const float* p1a_b  = (const float*)d_in[7];
    const float* p1b_w  = (const float*)d_in[8];
    const float* p1b_b  = (const float*)d_in[9];
    const float* lin2_w = (const float*)d_in[10];
    const float* lin2_b = (const float*)d_in[11];
    const float* p2a_w  = (const float*)d_in[12];
    const float* p2a_b  = (const float*)d_in[13];
    const float* p2b_w  = (const float*)d_in[14];
    const float* p2b_b  = (const float*)d_in[15];
    const float* cls_w  = (const float*)d_in[16];
    const float* cls_b  = (const float*)d_in[17];

    const int M = N_NODES_C;
    const int E = in_sizes[1] / 2;
    const size_t HS = (size_t)M * HIDDEN;          // ushorts per node matrix

    unsigned short* Hb0 = (unsigned short*)d_ws;   // h0 -> A2
    unsigned short* HA  = Hb0 + HS;                // A1 -> relu(h1)
    unsigned short* HB  = HA + HS;                 // B
    unsigned short* HL  = HB + HS;                 // L
    unsigned short* encT = HL + HS;                // [128][256]
    unsigned short* A1T = encT + 128 * 256;        // [128][128] each
    unsigned short* B1T = A1T + 128 * 128;
    unsigned short* L1T = B1T + 128 * 128;
    unsigned short* A2T = L1T + 128 * 128;
    unsigned short* B2T = A2T + 128 * 128;
    unsigned short* L2T = B2T + 128 * 128;
    int* deg   = (int*)(L2T + 128 * 128);          // M
    int* arr   = deg + M;                          // M+1 (CSR offsets, self-cursed)
    int* srcs  = arr + M + 1;                      // E
    int* bsums = srcs + E;                         // <=64

    const int ggrid = (M + 63) / 64;
    const int egrid = (E + 255) / 256;
    const int ngrid = (M + 3) / 4;
    const int sgrid = (M + 1023) / 1024;           // 49
    dim3 blk(256);

    // 1. prep: weights bf16-transpose + zero deg
    prep_kernel<<<64 + sgrid, blk, 0, stream>>>(enc_w, p1a_w, lin1_w, p2a_w, lin2_w,
                                                encT, A1T, B1T, L1T, A2T, B2T, L2T,
                                                deg, M);
    // 2-5. CSR build
    hist_kernel<<<egrid, blk, 0, stream>>>(ei, E, deg);
    scan_blocks<<<sgrid, blk, 0, stream>>>(deg, arr, bsums, M);
    scan_fixup<<<sgrid, blk, 0, stream>>>(arr, bsums, sgrid, M);
    scatter_kernel<<<egrid, blk, 0, stream>>>(ei, E, arr, srcs);

    // 6. encoder
    enc_mfma<<<ggrid, blk, 0, stream>>>(x, encT, enc_b, Hb0, M);

    // 7-8. layer 1
    fused3_mfma<<<ggrid, blk, 0, stream>>>(Hb0, A1T, B1T, L1T, lin1_b,
                                           HA, HB, HL, M);
    gather_bf16<false><<<ngrid, blk, 0, stream>>>(arr, srcs, HA, HB, HL,
                                                  p1a_b, p1b_w, p1b_b,
                                                  HA, nullptr, nullptr, nullptr, M);

    // 9-10. layer 2 (+ fused classifier)
    fused3_mfma<<<ggrid, blk, 0, stream>>>(HA, A2T, B2T, L2T, lin2_b,
                                           Hb0, HB, HL, M);
    gather_bf16<true><<<ngrid, blk, 0, stream>>>(arr, srcs, Hb0, HB, HL,
                                                 p2a_b, p2b_w, p2b_b,
                                                 nullptr, cls_w, cls_b,
                                                 (float*)d_out, M);
}